// Round 3
// baseline (208.063 us; speedup 1.0000x reference)
//
#include <hip/hip_runtime.h>
#include <hip/hip_cooperative_groups.h>
#include <math.h>

namespace cg = cooperative_groups;

// Problem constants (reference: N=8192, D=200, k=100)
#define NN 8192
#define DD 200
#define KK 100

// s = b_i + e_j histogram grid: 1024 bins over [-8, 8), width 2^-6 (exact fp)
#define NBINS 1024
#define HSCALE 64.0f
#define BINW 0.015625f
#define CAND_CAP 4096

// ws layout (4-byte word offsets)
#define OFF_B 0                    // float b[8192]
#define OFF_E 8192                 // float e[8192]
#define OFF_SB 16384               // float sum(exp b)   (atomic)
#define OFF_SE 16385               // float sum(exp e)   (atomic)
#define OFF_EMAXU 16386            // u32 ordered-encoded max(e) (atomicMax)
#define OFF_CC 16387               // u32 candidate count
#define OFF_HB 16388               // u32 hist_b[1024]
#define OFF_HE (OFF_HB + NBINS)    // u32 hist_e[1024]
#define OFF_CV (OFF_HE + NBINS)    // float cand_val[CAND_CAP]
#define OFF_CI (OFF_CV + CAND_CAP) // u32  cand_idx[CAND_CAP]
#define HDR_FIRST OFF_SB
#define HDR_WORDS (4 + 2 * NBINS)  // zeroed by memsetAsync each call

// order-preserving float<->uint encode for atomicMax on signed floats
__device__ inline unsigned f2o(float f) {
    unsigned u = __float_as_uint(f);
    return (u & 0x80000000u) ? ~u : (u | 0x80000000u);
}
__device__ inline float o2f(unsigned o) {
    unsigned u = (o & 0x80000000u) ? (o & 0x7FFFFFFFu) : ~o;
    return __uint_as_float(u);
}

__global__ __launch_bounds__(256) void k_all(const float* __restrict__ G,
                                             const float* __restrict__ wb,
                                             const float* __restrict__ we,
                                             float* __restrict__ wsf,
                                             unsigned* __restrict__ wsu,
                                             float* __restrict__ out) {
    cg::grid_group grid = cg::this_grid();
    __shared__ unsigned sm[8192];  // 32 KB, aliased per phase
    int tid = threadIdx.x, wave = tid >> 6, lane = tid & 63;

    // ---- Phase 1: b,e per row (wave-per-row), global-atomic hists/sums/max
    float eb = 0.f, ee = 0.f, em = -1e30f;  // lane0-valid accumulators
#pragma unroll
    for (int i = 0; i < 8; ++i) {
        int row = blockIdx.x * 32 + wave * 8 + i;
        float pb = 0.f, pe = 0.f;
        if (lane < 50) {
            float4 g = ((const float4*)(G + (size_t)row * DD))[lane];
            float4 B = ((const float4*)wb)[lane];
            float4 E = ((const float4*)we)[lane];
            pb = fmaf(g.x, B.x, fmaf(g.y, B.y, fmaf(g.z, B.z, g.w * B.w)));
            pe = fmaf(g.x, E.x, fmaf(g.y, E.y, fmaf(g.z, E.z, g.w * E.w)));
        }
        for (int off = 32; off; off >>= 1) {
            pb += __shfl_xor(pb, off, 64);
            pe += __shfl_xor(pe, off, 64);
        }
        if (lane == 0) {
            wsf[OFF_B + row] = pb;
            wsf[OFF_E + row] = pe;
            eb += expf(pb); ee += expf(pe); em = fmaxf(em, pe);
            int p = (int)fmaf(pb, HSCALE, 512.f); p = min(max(p, 0), NBINS - 1);
            int q = (int)fmaf(pe, HSCALE, 512.f); q = min(max(q, 0), NBINS - 1);
            atomicAdd(wsu + OFF_HB + p, 1u);
            atomicAdd(wsu + OFF_HE + q, 1u);
        }
    }
    if (lane == 0) {
        atomicAdd(wsf + OFF_SB, eb);
        atomicAdd(wsf + OFF_SE, ee);
        atomicMax(wsu + OFF_EMAXU, f2o(em));
    }
    grid.sync();

    // ---- Phase 2: redundant per-block threshold (binary search) + collect
    unsigned* sfx = sm;             // [1024] suffix sums of hist_e
    unsigned* hbl = sm + NBINS;     // [1024] hist_b copy
    unsigned* red = sm + 2 * NBINS; // [256] reduction scratch
    // load hist_e 4-consecutive per thread, local suffix
    unsigned v0 = wsu[OFF_HE + 4 * tid], v1 = wsu[OFF_HE + 4 * tid + 1];
    unsigned v2 = wsu[OFF_HE + 4 * tid + 2], v3 = wsu[OFF_HE + 4 * tid + 3];
    unsigned s3 = v3, s2 = v2 + s3, s1 = v1 + s2, s0 = v0 + s1;
    red[tid] = s0;
    for (int k = tid; k < NBINS; k += 256) hbl[k] = wsu[OFF_HB + k];
    __syncthreads();
    for (int d = 1; d < 256; d <<= 1) {  // Hillis-Steele suffix over thread totals
        unsigned v = (tid + d < 256) ? red[tid + d] : 0u;
        __syncthreads();
        red[tid] += v;
        __syncthreads();
    }
    unsigned tail = (tid < 255) ? red[tid + 1] : 0u;
    sfx[4 * tid + 0] = s0 + tail;
    sfx[4 * tid + 1] = s1 + tail;
    sfx[4 * tid + 2] = s2 + tail;
    sfx[4 * tid + 3] = s3 + tail;
    __syncthreads();
    // cnt(t) = sum_p hb[p] * sfx_e[t+512-p] — exact integer, monotone non-inc in t.
    // Binary search largest t with cnt >= 2*KK (same criterion as R2 => same t*).
    int lo = 0, hi = NBINS - 1;
    while (lo < hi) {
        int mid = (lo + hi + 1) >> 1;
        unsigned c = 0;
        for (int p = tid; p < NBINS; p += 256) {
            int idx = mid + 512 - p;
            unsigned sv = (idx <= 0) ? sfx[0] : ((idx > NBINS - 1) ? 0u : sfx[idx]);
            c += hbl[p] * sv;
        }
        red[tid] = c;
        __syncthreads();
        for (int off = 128; off; off >>= 1) {
            if (tid < off) red[tid] += red[tid + off];
            __syncthreads();
        }
        unsigned cnt = red[0];
        __syncthreads();
        if (cnt >= 2 * KK) lo = mid; else hi = mid - 1;
    }
    float thr = -8.0f + (float)(lo - 1) * BINW;  // one-bin safety margin (as R2)
    float emax = o2f(wsu[OFF_EMAXU]);
    const float* b = wsf + OFF_B;
    const float* e = wsf + OFF_E;
    for (int r = blockIdx.x; r < NN; r += 256) {
        float bi = b[r];
        if (bi + emax < thr) continue;  // row early-out
        for (int j = r + tid; j < NN; j += 256) {
            float s = bi + e[j];
            if (s >= thr) {
                unsigned pos = atomicAdd(wsu + OFF_CC, 1u);
                if (pos < CAND_CAP) {
                    wsf[OFF_CV + pos] = s;
                    wsu[OFF_CI + pos] = ((unsigned)r << 13) | (unsigned)j;
                }
            }
        }
    }
    grid.sync();

    // ---- Phase 3: block 0 rank-based top-100 (jax order: value desc, idx asc)
    if (blockIdx.x != 0) return;
    unsigned M = wsu[OFF_CC];
    if (M > CAND_CAP) M = CAND_CAP;
    float inv_den = 1.0f / (wsf[OFF_SB] * wsf[OFF_SE]);
    float* cv = (float*)sm;          // [4096]
    unsigned* ci = sm + CAND_CAP;    // [4096]
    for (unsigned c = tid; c < M; c += 256) {
        cv[c] = wsf[OFF_CV + c];
        ci[c] = wsu[OFF_CI + c];
    }
    __syncthreads();
    for (unsigned c = tid; c < M; c += 256) {
        float v = cv[c];
        unsigned fi = ci[c];
        int rank = 0;
        for (unsigned m = 0; m < M; ++m) {
            float vm = cv[m];
            rank += (vm > v) || (vm == v && ci[m] < fi);
        }
        if (rank < KK) {
            out[2 * rank]     = (float)(fi >> 13);
            out[2 * rank + 1] = (float)(fi & 8191u);
            out[200 + rank]   = expf(v) * inv_den;
        }
    }
}

extern "C" void kernel_launch(void* const* d_in, const int* in_sizes, int n_in,
                              void* d_out, int out_size, void* d_ws, size_t ws_size,
                              hipStream_t stream) {
    const float* G  = (const float*)d_in[0];
    const float* wb = (const float*)d_in[1];
    const float* we = (const float*)d_in[2];
    float* out = (float*)d_out;
    float* wsf = (float*)d_ws;
    unsigned* wsu = (unsigned*)d_ws;

    // zero the atomic header (sums, emax, counter, both hists)
    hipMemsetAsync((char*)d_ws + (size_t)HDR_FIRST * 4, 0, (size_t)HDR_WORDS * 4, stream);

    void* args[] = {(void*)&G, (void*)&wb, (void*)&we, (void*)&wsf, (void*)&wsu, (void*)&out};
    hipLaunchCooperativeKernel((const void*)k_all, dim3(256), dim3(256), args, 0, stream);
}